// Round 4
// baseline (394.553 us; speedup 1.0000x reference)
//
#include <hip/hip_runtime.h>
#include <hip/hip_bf16.h>
#include <math.h>

// Problem: Attention_58102317580396
// B=2, S=2048, D=2048, H=16, DH=128. Inputs/outputs FP32; internal bf16 MFMA.
// Pipeline: cvt(x,w_in,w_out)->bf16 ; GEMM1 x@w_in^T -> P[4096][6144] ;
//           flash attn -> O[4096][2048] ; GEMM2 O@w_out^T -> out fp32.
// R12: attn rewrite, KV tile 32 -> 64 keys/iteration (halves barriers,
// max/sum shuffle-reduce rounds, and rescale passes per key) + T13 defer-max
// (skip alpha-rescale when __all(mloc <= m_i+8); P bounded by e^8, bf16-safe)
// + per-wave causal diagonal skip (wave computes a tile only if
// kt*64 <= qRow+15; staging/barriers still run) + f-outer QK MFMA order
// (4 independent MFMAs between dependent accumulates).
// LDS 69 KiB (sK 2x16KB, sVt 2x18.4KB pitch 72) — kept under 80 so 2 blocks/CU
// co-residency survives (512 blocks = exactly 2/CU). GEMM1 (gemm_bt<128>,
// 125.5us measured), GEMM2 (gemm_bt<128,f32out>), cvt unchanged.
// Verified layouts (learn_hip m89/m120):
//   A-frag: m=lane&15, k=quad*8+j ; B-frag: n=lane&15, k=quad*8+j (same addr)
//   C/D:    col=lane&15, row=quad*4+reg

typedef short bf16x8 __attribute__((ext_vector_type(8)));
typedef float f32x4 __attribute__((ext_vector_type(4)));

#define NEG_BIG -30000.0f

__device__ __forceinline__ short f2bf(float f) {
    union { float f; unsigned u; } v; v.f = f;
    unsigned r = v.u + 0x7fffu + ((v.u >> 16) & 1u);  // RNE
    return (short)(r >> 16);
}

__device__ __forceinline__ int pack2bf(float a, float b) {
    return (int)((((unsigned)f2bf(b)) << 16) | (((unsigned)f2bf(a)) & 0xffffu));
}

#define GLDS16(g, l) \
    __builtin_amdgcn_global_load_lds((const __attribute__((address_space(1))) void*)(g), \
                                     (__attribute__((address_space(3))) void*)(l), 16, 0, 0)

// fp32 -> bf16 elementwise (n divisible by 1024)
__global__ __launch_bounds__(256) void cvt_f32_bf16(const float* __restrict__ src,
                                                    short* __restrict__ dst, int n) {
    int i = (blockIdx.x * blockDim.x + threadIdx.x) * 4;
    if (i < n) {
        float4 v = *(const float4*)(src + i);
        short4 o;
        o.x = f2bf(v.x); o.y = f2bf(v.y); o.z = f2bf(v.z); o.w = f2bf(v.w);
        *(short4*)(dst + i) = o;
    }
}

// C[M][N] = A[M][K] * B[N][K]^T  (bf16 in, fp32 acc, bf16 or fp32 out)
// block 256 = 4 waves; block tile 128xBN; wave tile 64x(BN/2); BK=64 as two
// 32-k sub-tiles per barrier pair. LDS layout per sub: chunk-ordered rows x32.
template <int BN, bool F32OUT>
__global__ __launch_bounds__(256) void gemm_bt(const short* __restrict__ A,
                                               const short* __restrict__ Bm,
                                               void* __restrict__ Cv,
                                               int N, int K) {
    constexpr int NT = BN / 32;               // n-acc tiles per wave
    constexpr int SUBA = 128 * 32;            // shorts per A sub-tile
    constexpr int SUBB = BN * 32;             // shorts per B sub-tile
    __shared__ short sA[2 * SUBA];
    __shared__ short sB[2 * SUBB];
    const int lane = threadIdx.x & 63;
    const int w = threadIdx.x >> 6;
    const int l15 = lane & 15, quad = lane >> 4;
    const int bm0 = blockIdx.y * 128, bn0 = blockIdx.x * BN;

    const int c1 = w * 64 + lane;             // chunk id 0..255
    const short* gA = A + (size_t)(bm0 + (c1 >> 2)) * K + (c1 & 3) * 8;
    const short* gB = Bm + (size_t)(bn0 + (c1 >> 2)) * K + (c1 & 3) * 8;
    const size_t half64 = (size_t)64 * K;     // chunk +256 -> row +64
    short* lA1 = sA + w * 512;                // wave-uniform GLDS bases
    short* lA2 = sA + 2048 + w * 512;
    short* lB1 = sB + w * 512;
    short* lB2 = sB + 2048 + w * 512;         // only when BN==128

    const int wm = (w >> 1) * 64, wn = (w & 1) * (BN / 2);
    const short* pa = sA + (wm + l15) * 32 + quad * 8;
    const short* pb = sB + (wn + l15) * 32 + quad * 8;

    f32x4 acc[4][NT] = {};
    for (int k0 = 0; k0 < K; k0 += 64) {
        #pragma unroll
        for (int s = 0; s < 2; s++) {
            const int ks = k0 + s * 32;
            GLDS16(gA + ks, lA1 + s * SUBA);
            GLDS16(gA + half64 + ks, lA2 + s * SUBA);
            GLDS16(gB + ks, lB1 + s * SUBB);
            if constexpr (BN == 128) GLDS16(gB + half64 + ks, lB2 + s * SUBB);
        }
        __syncthreads();
        #pragma unroll
        for (int s = 0; s < 2; s++) {
            bf16x8 af[4], bf[NT];
            #pragma unroll
            for (int mt = 0; mt < 4; mt++) af[mt] = *(const bf16x8*)(pa + s * SUBA + mt * 512);
            #pragma unroll
            for (int nt = 0; nt < NT; nt++) bf[nt] = *(const bf16x8*)(pb + s * SUBB + nt * 512);
            #pragma unroll
            for (int mt = 0; mt < 4; mt++)
                #pragma unroll
                for (int nt = 0; nt < NT; nt++)
                    acc[mt][nt] = __builtin_amdgcn_mfma_f32_16x16x32_bf16(af[mt], bf[nt], acc[mt][nt], 0, 0, 0);
        }
        __syncthreads();
    }
    #pragma unroll
    for (int mt = 0; mt < 4; mt++)
        #pragma unroll
        for (int nt = 0; nt < NT; nt++)
            #pragma unroll
            for (int r = 0; r < 4; r++) {
                int row = bm0 + wm + mt * 16 + quad * 4 + r;
                int col = bn0 + wn + nt * 16 + l15;
                if (F32OUT)
                    ((float*)Cv)[(size_t)row * N + col] = acc[mt][nt][r];
                else
                    ((short*)Cv)[(size_t)row * N + col] = f2bf(acc[mt][nt][r]);
            }
}

// ---------------------------------------------------------------------------
// Flash attention, causal, S^T formulation. q-tile 128 rows, 8 waves (512 thr).
// grid = 512 blocks; qt = b ? 15-t0 : t0 so co-resident pairs (ids +256) do
// constant work. KV tile = 64 keys/iter. Waves 0-3 stage K (4x GLDS,
// XOR-swizzled), waves 4-7 stage V (transposed, pitch 72). Per-wave compute:
// 16 q-rows; waves skip tiles fully above their causal diagonal.
#define VP2 72
__global__ __launch_bounds__(512) void attn_kernel(const short* __restrict__ P,
                                                   short* __restrict__ O) {
    constexpr int S = 2048, ROWW = 6144, HD = 2048;
    const int id = blockIdx.x;
    const int b = id >> 8;
    const int rr = id & 255;
    const int h = rr & 15;
    const int t0 = rr >> 4;                    // 0..15
    const int qt = b ? (15 - t0) : t0;         // work balance across pairs
    const int wave = threadIdx.x >> 6, lane = threadIdx.x & 63;
    const int l15 = lane & 15, quad = lane >> 4;
    const int qRow = qt * 128 + wave * 16;
    const short* Pb = P + (size_t)b * S * ROWW;
    const short* Qp = Pb + h * 384;
    const short* Kp = Qp + 128;
    const short* Vp = Qp + 256;

    __shared__ short sK[2][64 * 128];   // swizzled chunk layout, 16 KB each
    __shared__ short sVt[2][128 * VP2]; // [d][key], 18.4 KB each

    // Q fragments (B operand, n=q=l15, k=d=quad*8+j)
    bf16x8 qf[4];
    #pragma unroll
    for (int f = 0; f < 4; f++)
        qf[f] = *(const bf16x8*)(Qp + (size_t)(qRow + l15) * ROWW + f * 32 + quad * 8);

    const bool isK = wave < 4;
    const int c1 = (wave & 3) * 64 + lane;
    const int krow1 = c1 >> 4;                 // 0..15
    const int kcol = ((c1 & 15) ^ (krow1 & 15)) * 8;
    const short* gK1 = Kp + (size_t)krow1 * ROWW + kcol;
    const short* gK2 = Kp + (size_t)(krow1 + 16) * ROWW + kcol;
    const short* gK3 = Kp + (size_t)(krow1 + 32) * ROWW + kcol;
    const short* gK4 = Kp + (size_t)(krow1 + 48) * ROWW + kcol;
    const int ldsOff1 = (wave & 3) * 512;
    const int ldsOff2 = 2048 + ldsOff1;
    const int ldsOff3 = 4096 + ldsOff1;
    const int ldsOff4 = 6144 + ldsOff1;
    const int vt = (int)threadIdx.x - 256;
    const int vKey = vt & 31;
    const int vD0 = (vt >> 5) * 8;
    const short* gV = Vp + (size_t)vKey * ROWW + vD0;
    const short* gV2 = Vp + (size_t)(vKey + 32) * ROWW + vD0;

    const int kTiles = qt * 2 + 2;             // 64-key tiles
    const float scale = 0.08838834764831845f;  // 1/sqrt(128)
    const int qG = qRow + l15;

    f32x4 accO[8] = {};                        // O^T: row=d(quad*4+r), col=q(l15)
    float m_i = NEG_BIG, l_i = 0.f;

    if (isK) {
        GLDS16(gK1, &sK[0][ldsOff1]);
        GLDS16(gK2, &sK[0][ldsOff2]);
        GLDS16(gK3, &sK[0][ldsOff3]);
        GLDS16(gK4, &sK[0][ldsOff4]);
    } else {
        bf16x8 v0 = *(const bf16x8*)(gV);
        bf16x8 v1 = *(const bf16x8*)(gV + 64);
        bf16x8 v2 = *(const bf16x8*)(gV2);
        bf16x8 v3 = *(const bf16x8*)(gV2 + 64);
        #pragma unroll
        for (int j = 0; j < 8; j++) {
            sVt[0][(vD0 + j) * VP2 + vKey] = v0[j];
            sVt[0][(vD0 + 64 + j) * VP2 + vKey] = v1[j];
            sVt[0][(vD0 + j) * VP2 + vKey + 32] = v2[j];
            sVt[0][(vD0 + 64 + j) * VP2 + vKey + 32] = v3[j];
        }
    }
    __syncthreads();

    for (int kt = 0; kt < kTiles; kt++) {
        const int cur = kt & 1, nxt = cur ^ 1;
        const bool pre = (kt + 1 < kTiles);
        bf16x8 v0n, v1n, v2n, v3n;
        if (pre) {
            const size_t kOff = (size_t)(kt + 1) * 64 * ROWW;
            if (isK) {
                GLDS16(gK1 + kOff, &sK[nxt][ldsOff1]);
                GLDS16(gK2 + kOff, &sK[nxt][ldsOff2]);
                GLDS16(gK3 + kOff, &sK[nxt][ldsOff3]);
                GLDS16(gK4 + kOff, &sK[nxt][ldsOff4]);
            } else {
                v0n = *(const bf16x8*)(gV + kOff);
                v1n = *(const bf16x8*)(gV + kOff + 64);
                v2n = *(const bf16x8*)(gV2 + kOff);
                v3n = *(const bf16x8*)(gV2 + kOff + 64);
            }
        }
        if (kt * 64 <= qRow + 15) {  // wave-uniform causal diagonal skip
            // QK^T transposed: sc[hh] row=key(hh*16+quad*4+r), col=q(l15)
            f32x4 sc[4] = {};
            #pragma unroll
            for (int f = 0; f < 4; f++) {       // f-outer: 4 indep MFMA chains
                const int jj = ((4 * f + quad) ^ l15) * 8;
                #pragma unroll
                for (int hh = 0; hh < 4; hh++) {
                    bf16x8 kf = *(const bf16x8*)(&sK[cur][(hh * 16 + l15) * 128 + jj]);
                    sc[hh] = __builtin_amdgcn_mfma_f32_16x16x32_bf16(kf, qf[f], sc[hh], 0, 0, 0);
                }
            }
            #pragma unroll
            for (int hh = 0; hh < 4; hh++)
                #pragma unroll
                for (int r = 0; r < 4; r++) {
                    int key = kt * 64 + hh * 16 + quad * 4 + r;
                    float v = sc[hh][r] * scale;
                    sc[hh][r] = (key <= qG) ? v : NEG_BIG;
                }
            float mloc = sc[0][0];
            #pragma unroll
            for (int hh = 0; hh < 4; hh++)
                #pragma unroll
                for (int r = 0; r < 4; r++) mloc = fmaxf(mloc, sc[hh][r]);
            mloc = fmaxf(mloc, __shfl_xor(mloc, 16));
            mloc = fmaxf(mloc, __shfl_xor(mloc, 32));
            if (!__all(mloc <= m_i + 8.0f)) {  // T13 defer-max (THR=8)
                const float nm = fmaxf(m_i, mloc);
                const float alpha = __expf(m_i - nm);
                m_i = nm;
                l_i *= alpha;
                #pragma unroll
                for (int t = 0; t < 8; t++)
                    #pragma unroll
                    for (int r = 0; r < 4; r++) accO[t][r] *= alpha;
            }
            float ssum = 0.f;
            #pragma unroll
            for (int hh = 0; hh < 4; hh++)
                #pragma unroll
                for (int r = 0; r < 4; r++) {
                    float p = __expf(sc[hh][r] - m_i);
                    sc[hh][r] = p;
                    ssum += p;
                }
            ssum += __shfl_xor(ssum, 16);
            ssum += __shfl_xor(ssum, 32);
            l_i += ssum;
            // P^T (C-layout) -> B-frag via 8 shfl per 32-key slot; PV per slot
            #pragma unroll
            for (int s = 0; s < 2; s++) {
                const int d00 = pack2bf(sc[2 * s][0], sc[2 * s][1]);
                const int d01 = pack2bf(sc[2 * s][2], sc[2 * s][3]);
                const int d10 = pack2bf(sc[2 * s + 1][0], sc[2 * s + 1][1]);
                const int d11 = pack2bf(sc[2 * s + 1][2], sc[2 * s + 1][3]);
                const int srcA = l15 + ((quad & 1) << 5);
                const int srcB = srcA + 16;
                const int s00 = __shfl(d00, srcA), s01 = __shfl(d01, srcA);
                const int s02 = __shfl(d00, srcB), s03 = __shfl(d01, srcB);
                const int s10 = __shfl(d10, srcA), s11 = __shfl(d11, srcA);
                const int s12 = __shfl(d10, srcB), s13 = __shfl(d11, srcB);
                union { int i[4]; bf16x8 v; } pu;
                const bool lo = quad < 2;
                pu.i[0] = lo ? s00 : s10;
                pu.i[1] = lo ? s01 : s11;
                pu.i[2] = lo ? s02 : s12;
                pu.i[3] = lo ? s03 : s13;
                const bf16x8 pf = pu.v;
                // PV: O^T += V^T * P^T (keys s*32..s*32+31)
                #pragma unroll
                for (int t = 0; t < 8; t++) {
                    bf16x8 vf = *(const bf16x8*)(&sVt[cur][(t * 16 + l15) * VP2 + s * 32 + quad * 8]);
                    accO[t] = __builtin_amdgcn_mfma_f32_16x16x32_bf16(vf, pf, accO[t], 0, 0, 0);
                }
            }
        }
        if (pre && !isK) {
            #pragma unroll
            for (int j = 0; j < 8; j++) {
                sVt[nxt][(vD0 + j) * VP2 + vKey] = v0n[j];
                sVt[nxt][(vD0 + 64 + j) * VP2 + vKey] = v1n[j];
                sVt[nxt][(vD0 + j) * VP2 + vKey + 32] = v2n[j];
                sVt[nxt][(vD0 + 64 + j) * VP2 + vKey + 32] = v3n[j];
            }
        }
        __syncthreads();
    }
    const float inv = 1.0f / l_i;
    #pragma unroll
    for (int t = 0; t < 8; t++) {
        short4 st;
        st.x = f2bf(accO[t][0] * inv);
        st.y = f2bf(accO[t][1] * inv);
        st.z = f2bf(accO[t][2] * inv);
        st.w = f2bf(accO[t][3] * inv);
        *(short4*)(&O[(size_t)(b * S + qG) * HD + h * 128 + t * 16 + quad * 4]) = st;
    }
}

extern "C" void kernel_launch(void* const* d_in, const int* in_sizes, int n_in,
                              void* d_out, int out_size, void* d_ws, size_t ws_size,
                              hipStream_t stream) {
    const float* x     = (const float*)d_in[0];  // [2,2048,2048] fp32
    const float* w_in  = (const float*)d_in[1];  // [6144,2048]  fp32
    const float* w_out = (const float*)d_in[2];  // [2048,2048]  fp32
    float* out = (float*)d_out;                  // [2,2048,2048] fp32

    // Workspace (96 MiB): P[4096*6144] bf16 | xO[8388608] bf16 (x_bf16 then O)
    //                     | w_in_b[6144*2048] bf16 | w_out_b[2048*2048] bf16
    short* Pbuf   = (short*)d_ws;
    short* xObuf  = Pbuf  + (size_t)4096 * 6144;
    short* winb   = xObuf + (size_t)8388608;
    short* woutb  = winb  + (size_t)6144 * 2048;

    dim3 blk(256, 1, 1);
    const int nx = 2 * 2048 * 2048, nwi = 6144 * 2048, nwo = 2048 * 2048;
    hipLaunchKernelGGL(cvt_f32_bf16, dim3(nx / 1024), blk, 0, stream, x, xObuf, nx);
    hipLaunchKernelGGL(cvt_f32_bf16, dim3(nwi / 1024), blk, 0, stream, w_in, winb, nwi);
    hipLaunchKernelGGL(cvt_f32_bf16, dim3(nwo / 1024), blk, 0, stream, w_out, woutb, nwo);
    // GEMM1: P = x @ w_in^T   (M=4096, N=6144, K=2048), bf16 out, BN=128 BK=64
    hipLaunchKernelGGL((gemm_bt<128, false>), dim3(48, 32, 1), blk, 0, stream, xObuf, winb, (void*)Pbuf, 6144, 2048);
    // Flash attention (x_bf16 dead now; O overwrites it), 512 blocks x 512 thr
    hipLaunchKernelGGL(attn_kernel, dim3(512, 1, 1), dim3(512, 1, 1), 0, stream, Pbuf, xObuf);
    // GEMM2: out = O @ w_out^T (M=4096, N=2048, K=2048), fp32 out, BN=128 BK=64
    hipLaunchKernelGGL((gemm_bt<128, true>), dim3(16, 32, 1), blk, 0, stream, xObuf, woutb, (void*)out, 2048, 2048);
}

// Round 5
// 388.540 us; speedup vs baseline: 1.0155x; 1.0155x over previous
//
#include <hip/hip_runtime.h>
#include <hip/hip_bf16.h>
#include <math.h>

// Problem: Attention_58102317580396
// B=2, S=2048, D=2048, H=16, DH=128. Inputs/outputs FP32; internal bf16 MFMA.
// Pipeline: cvt(x,w_in,w_out)->bf16 ; GEMM1 x@w_in^T -> P[4096][6144] ;
//           flash attn -> O[4096][2048] ; GEMM2 O@w_out^T -> out fp32.
// R13: MEASUREMENT ROUND. GEMM1 split into two M-half dispatches (dim3(48,16)
// each, 768 blocks = 3 CU-rounds; total rounds unchanged -> perf-neutral,
// ~+2us launch overhead). Purpose: GEMM1's ~125us dispatches monopolized the
// top-5 counter table; halving per-dispatch time (~63us) forces attn_kernel
// and GEMM2 into the top-5 so their duration/MfmaUtil/VALUBusy/occupancy are
// finally measured instead of inferred (3 consecutive missed predictions on
// unmeasured kernels). attn (R12 64-key version), GEMM2 (gemm_bt<128,f32>),
// cvt unchanged.
// Verified layouts (learn_hip m89/m120):
//   A-frag: m=lane&15, k=quad*8+j ; B-frag: n=lane&15, k=quad*8+j (same addr)
//   C/D:    col=lane&15, row=quad*4+reg

typedef short bf16x8 __attribute__((ext_vector_type(8)));
typedef float f32x4 __attribute__((ext_vector_type(4)));

#define NEG_BIG -30000.0f

__device__ __forceinline__ short f2bf(float f) {
    union { float f; unsigned u; } v; v.f = f;
    unsigned r = v.u + 0x7fffu + ((v.u >> 16) & 1u);  // RNE
    return (short)(r >> 16);
}

__device__ __forceinline__ int pack2bf(float a, float b) {
    return (int)((((unsigned)f2bf(b)) << 16) | (((unsigned)f2bf(a)) & 0xffffu));
}

#define GLDS16(g, l) \
    __builtin_amdgcn_global_load_lds((const __attribute__((address_space(1))) void*)(g), \
                                     (__attribute__((address_space(3))) void*)(l), 16, 0, 0)

// fp32 -> bf16 elementwise (n divisible by 1024)
__global__ __launch_bounds__(256) void cvt_f32_bf16(const float* __restrict__ src,
                                                    short* __restrict__ dst, int n) {
    int i = (blockIdx.x * blockDim.x + threadIdx.x) * 4;
    if (i < n) {
        float4 v = *(const float4*)(src + i);
        short4 o;
        o.x = f2bf(v.x); o.y = f2bf(v.y); o.z = f2bf(v.z); o.w = f2bf(v.w);
        *(short4*)(dst + i) = o;
    }
}

// C[M][N] = A[M][K] * B[N][K]^T  (bf16 in, fp32 acc, bf16 or fp32 out)
// block 256 = 4 waves; block tile 128xBN; wave tile 64x(BN/2); BK=64 as two
// 32-k sub-tiles per barrier pair. LDS layout per sub: chunk-ordered rows x32.
template <int BN, bool F32OUT>
__global__ __launch_bounds__(256) void gemm_bt(const short* __restrict__ A,
                                               const short* __restrict__ Bm,
                                               void* __restrict__ Cv,
                                               int N, int K) {
    constexpr int NT = BN / 32;               // n-acc tiles per wave
    constexpr int SUBA = 128 * 32;            // shorts per A sub-tile
    constexpr int SUBB = BN * 32;             // shorts per B sub-tile
    __shared__ short sA[2 * SUBA];
    __shared__ short sB[2 * SUBB];
    const int lane = threadIdx.x & 63;
    const int w = threadIdx.x >> 6;
    const int l15 = lane & 15, quad = lane >> 4;
    const int bm0 = blockIdx.y * 128, bn0 = blockIdx.x * BN;

    const int c1 = w * 64 + lane;             // chunk id 0..255
    const short* gA = A + (size_t)(bm0 + (c1 >> 2)) * K + (c1 & 3) * 8;
    const short* gB = Bm + (size_t)(bn0 + (c1 >> 2)) * K + (c1 & 3) * 8;
    const size_t half64 = (size_t)64 * K;     // chunk +256 -> row +64
    short* lA1 = sA + w * 512;                // wave-uniform GLDS bases
    short* lA2 = sA + 2048 + w * 512;
    short* lB1 = sB + w * 512;
    short* lB2 = sB + 2048 + w * 512;         // only when BN==128

    const int wm = (w >> 1) * 64, wn = (w & 1) * (BN / 2);
    const short* pa = sA + (wm + l15) * 32 + quad * 8;
    const short* pb = sB + (wn + l15) * 32 + quad * 8;

    f32x4 acc[4][NT] = {};
    for (int k0 = 0; k0 < K; k0 += 64) {
        #pragma unroll
        for (int s = 0; s < 2; s++) {
            const int ks = k0 + s * 32;
            GLDS16(gA + ks, lA1 + s * SUBA);
            GLDS16(gA + half64 + ks, lA2 + s * SUBA);
            GLDS16(gB + ks, lB1 + s * SUBB);
            if constexpr (BN == 128) GLDS16(gB + half64 + ks, lB2 + s * SUBB);
        }
        __syncthreads();
        #pragma unroll
        for (int s = 0; s < 2; s++) {
            bf16x8 af[4], bf[NT];
            #pragma unroll
            for (int mt = 0; mt < 4; mt++) af[mt] = *(const bf16x8*)(pa + s * SUBA + mt * 512);
            #pragma unroll
            for (int nt = 0; nt < NT; nt++) bf[nt] = *(const bf16x8*)(pb + s * SUBB + nt * 512);
            #pragma unroll
            for (int mt = 0; mt < 4; mt++)
                #pragma unroll
                for (int nt = 0; nt < NT; nt++)
                    acc[mt][nt] = __builtin_amdgcn_mfma_f32_16x16x32_bf16(af[mt], bf[nt], acc[mt][nt], 0, 0, 0);
        }
        __syncthreads();
    }
    #pragma unroll
    for (int mt = 0; mt < 4; mt++)
        #pragma unroll
        for (int nt = 0; nt < NT; nt++)
            #pragma unroll
            for (int r = 0; r < 4; r++) {
                int row = bm0 + wm + mt * 16 + quad * 4 + r;
                int col = bn0 + wn + nt * 16 + l15;
                if (F32OUT)
                    ((float*)Cv)[(size_t)row * N + col] = acc[mt][nt][r];
                else
                    ((short*)Cv)[(size_t)row * N + col] = f2bf(acc[mt][nt][r]);
            }
}

// ---------------------------------------------------------------------------
// Flash attention, causal, S^T formulation. q-tile 128 rows, 8 waves (512 thr).
// grid = 512 blocks; qt = b ? 15-t0 : t0 so co-resident pairs (ids +256) do
// constant work. KV tile = 64 keys/iter. Waves 0-3 stage K (4x GLDS,
// XOR-swizzled), waves 4-7 stage V (transposed, pitch 72). Per-wave compute:
// 16 q-rows; waves skip tiles fully above their causal diagonal.
#define VP2 72
__global__ __launch_bounds__(512) void attn_kernel(const short* __restrict__ P,
                                                   short* __restrict__ O) {
    constexpr int S = 2048, ROWW = 6144, HD = 2048;
    const int id = blockIdx.x;
    const int b = id >> 8;
    const int rr = id & 255;
    const int h = rr & 15;
    const int t0 = rr >> 4;                    // 0..15
    const int qt = b ? (15 - t0) : t0;         // work balance across pairs
    const int wave = threadIdx.x >> 6, lane = threadIdx.x & 63;
    const int l15 = lane & 15, quad = lane >> 4;
    const int qRow = qt * 128 + wave * 16;
    const short* Pb = P + (size_t)b * S * ROWW;
    const short* Qp = Pb + h * 384;
    const short* Kp = Qp + 128;
    const short* Vp = Qp + 256;

    __shared__ short sK[2][64 * 128];   // swizzled chunk layout, 16 KB each
    __shared__ short sVt[2][128 * VP2]; // [d][key], 18.4 KB each

    // Q fragments (B operand, n=q=l15, k=d=quad*8+j)
    bf16x8 qf[4];
    #pragma unroll
    for (int f = 0; f < 4; f++)
        qf[f] = *(const bf16x8*)(Qp + (size_t)(qRow + l15) * ROWW + f * 32 + quad * 8);

    const bool isK = wave < 4;
    const int c1 = (wave & 3) * 64 + lane;
    const int krow1 = c1 >> 4;                 // 0..15
    const int kcol = ((c1 & 15) ^ (krow1 & 15)) * 8;
    const short* gK1 = Kp + (size_t)krow1 * ROWW + kcol;
    const short* gK2 = Kp + (size_t)(krow1 + 16) * ROWW + kcol;
    const short* gK3 = Kp + (size_t)(krow1 + 32) * ROWW + kcol;
    const short* gK4 = Kp + (size_t)(krow1 + 48) * ROWW + kcol;
    const int ldsOff1 = (wave & 3) * 512;
    const int ldsOff2 = 2048 + ldsOff1;
    const int ldsOff3 = 4096 + ldsOff1;
    const int ldsOff4 = 6144 + ldsOff1;
    const int vt = (int)threadIdx.x - 256;
    const int vKey = vt & 31;
    const int vD0 = (vt >> 5) * 8;
    const short* gV = Vp + (size_t)vKey * ROWW + vD0;
    const short* gV2 = Vp + (size_t)(vKey + 32) * ROWW + vD0;

    const int kTiles = qt * 2 + 2;             // 64-key tiles
    const float scale = 0.08838834764831845f;  // 1/sqrt(128)
    const int qG = qRow + l15;

    f32x4 accO[8] = {};                        // O^T: row=d(quad*4+r), col=q(l15)
    float m_i = NEG_BIG, l_i = 0.f;

    if (isK) {
        GLDS16(gK1, &sK[0][ldsOff1]);
        GLDS16(gK2, &sK[0][ldsOff2]);
        GLDS16(gK3, &sK[0][ldsOff3]);
        GLDS16(gK4, &sK[0][ldsOff4]);
    } else {
        bf16x8 v0 = *(const bf16x8*)(gV);
        bf16x8 v1 = *(const bf16x8*)(gV + 64);
        bf16x8 v2 = *(const bf16x8*)(gV2);
        bf16x8 v3 = *(const bf16x8*)(gV2 + 64);
        #pragma unroll
        for (int j = 0; j < 8; j++) {
            sVt[0][(vD0 + j) * VP2 + vKey] = v0[j];
            sVt[0][(vD0 + 64 + j) * VP2 + vKey] = v1[j];
            sVt[0][(vD0 + j) * VP2 + vKey + 32] = v2[j];
            sVt[0][(vD0 + 64 + j) * VP2 + vKey + 32] = v3[j];
        }
    }
    __syncthreads();

    for (int kt = 0; kt < kTiles; kt++) {
        const int cur = kt & 1, nxt = cur ^ 1;
        const bool pre = (kt + 1 < kTiles);
        bf16x8 v0n, v1n, v2n, v3n;
        if (pre) {
            const size_t kOff = (size_t)(kt + 1) * 64 * ROWW;
            if (isK) {
                GLDS16(gK1 + kOff, &sK[nxt][ldsOff1]);
                GLDS16(gK2 + kOff, &sK[nxt][ldsOff2]);
                GLDS16(gK3 + kOff, &sK[nxt][ldsOff3]);
                GLDS16(gK4 + kOff, &sK[nxt][ldsOff4]);
            } else {
                v0n = *(const bf16x8*)(gV + kOff);
                v1n = *(const bf16x8*)(gV + kOff + 64);
                v2n = *(const bf16x8*)(gV2 + kOff);
                v3n = *(const bf16x8*)(gV2 + kOff + 64);
            }
        }
        if (kt * 64 <= qRow + 15) {  // wave-uniform causal diagonal skip
            // QK^T transposed: sc[hh] row=key(hh*16+quad*4+r), col=q(l15)
            f32x4 sc[4] = {};
            #pragma unroll
            for (int f = 0; f < 4; f++) {       // f-outer: 4 indep MFMA chains
                const int jj = ((4 * f + quad) ^ l15) * 8;
                #pragma unroll
                for (int hh = 0; hh < 4; hh++) {
                    bf16x8 kf = *(const bf16x8*)(&sK[cur][(hh * 16 + l15) * 128 + jj]);
                    sc[hh] = __builtin_amdgcn_mfma_f32_16x16x32_bf16(kf, qf[f], sc[hh], 0, 0, 0);
                }
            }
            #pragma unroll
            for (int hh = 0; hh < 4; hh++)
                #pragma unroll
                for (int r = 0; r < 4; r++) {
                    int key = kt * 64 + hh * 16 + quad * 4 + r;
                    float v = sc[hh][r] * scale;
                    sc[hh][r] = (key <= qG) ? v : NEG_BIG;
                }
            float mloc = sc[0][0];
            #pragma unroll
            for (int hh = 0; hh < 4; hh++)
                #pragma unroll
                for (int r = 0; r < 4; r++) mloc = fmaxf(mloc, sc[hh][r]);
            mloc = fmaxf(mloc, __shfl_xor(mloc, 16));
            mloc = fmaxf(mloc, __shfl_xor(mloc, 32));
            if (!__all(mloc <= m_i + 8.0f)) {  // T13 defer-max (THR=8)
                const float nm = fmaxf(m_i, mloc);
                const float alpha = __expf(m_i - nm);
                m_i = nm;
                l_i *= alpha;
                #pragma unroll
                for (int t = 0; t < 8; t++)
                    #pragma unroll
                    for (int r = 0; r < 4; r++) accO[t][r] *= alpha;
            }
            float ssum = 0.f;
            #pragma unroll
            for (int hh = 0; hh < 4; hh++)
                #pragma unroll
                for (int r = 0; r < 4; r++) {
                    float p = __expf(sc[hh][r] - m_i);
                    sc[hh][r] = p;
                    ssum += p;
                }
            ssum += __shfl_xor(ssum, 16);
            ssum += __shfl_xor(ssum, 32);
            l_i += ssum;
            // P^T (C-layout) -> B-frag via 8 shfl per 32-key slot; PV per slot
            #pragma unroll
            for (int s = 0; s < 2; s++) {
                const int d00 = pack2bf(sc[2 * s][0], sc[2 * s][1]);
                const int d01 = pack2bf(sc[2 * s][2], sc[2 * s][3]);
                const int d10 = pack2bf(sc[2 * s + 1][0], sc[2 * s + 1][1]);
                const int d11 = pack2bf(sc[2 * s + 1][2], sc[2 * s + 1][3]);
                const int srcA = l15 + ((quad & 1) << 5);
                const int srcB = srcA + 16;
                const int s00 = __shfl(d00, srcA), s01 = __shfl(d01, srcA);
                const int s02 = __shfl(d00, srcB), s03 = __shfl(d01, srcB);
                const int s10 = __shfl(d10, srcA), s11 = __shfl(d11, srcA);
                const int s12 = __shfl(d10, srcB), s13 = __shfl(d11, srcB);
                union { int i[4]; bf16x8 v; } pu;
                const bool lo = quad < 2;
                pu.i[0] = lo ? s00 : s10;
                pu.i[1] = lo ? s01 : s11;
                pu.i[2] = lo ? s02 : s12;
                pu.i[3] = lo ? s03 : s13;
                const bf16x8 pf = pu.v;
                // PV: O^T += V^T * P^T (keys s*32..s*32+31)
                #pragma unroll
                for (int t = 0; t < 8; t++) {
                    bf16x8 vf = *(const bf16x8*)(&sVt[cur][(t * 16 + l15) * VP2 + s * 32 + quad * 8]);
                    accO[t] = __builtin_amdgcn_mfma_f32_16x16x32_bf16(vf, pf, accO[t], 0, 0, 0);
                }
            }
        }
        if (pre && !isK) {
            #pragma unroll
            for (int j = 0; j < 8; j++) {
                sVt[nxt][(vD0 + j) * VP2 + vKey] = v0n[j];
                sVt[nxt][(vD0 + 64 + j) * VP2 + vKey] = v1n[j];
                sVt[nxt][(vD0 + j) * VP2 + vKey + 32] = v2n[j];
                sVt[nxt][(vD0 + 64 + j) * VP2 + vKey + 32] = v3n[j];
            }
        }
        __syncthreads();
    }
    const float inv = 1.0f / l_i;
    #pragma unroll
    for (int t = 0; t < 8; t++) {
        short4 st;
        st.x = f2bf(accO[t][0] * inv);
        st.y = f2bf(accO[t][1] * inv);
        st.z = f2bf(accO[t][2] * inv);
        st.w = f2bf(accO[t][3] * inv);
        *(short4*)(&O[(size_t)(b * S + qG) * HD + h * 128 + t * 16 + quad * 4]) = st;
    }
}

extern "C" void kernel_launch(void* const* d_in, const int* in_sizes, int n_in,
                              void* d_out, int out_size, void* d_ws, size_t ws_size,
                              hipStream_t stream) {
    const float* x     = (const float*)d_in[0];  // [2,2048,2048] fp32
    const float* w_in  = (const float*)d_in[1];  // [6144,2048]  fp32
    const float* w_out = (const float*)d_in[2];  // [2048,2048]  fp32
    float* out = (float*)d_out;                  // [2,2048,2048] fp32

    // Workspace (96 MiB): P[4096*6144] bf16 | xO[8388608] bf16 (x_bf16 then O)
    //                     | w_in_b[6144*2048] bf16 | w_out_b[2048*2048] bf16
    short* Pbuf   = (short*)d_ws;
    short* xObuf  = Pbuf  + (size_t)4096 * 6144;
    short* winb   = xObuf + (size_t)8388608;
    short* woutb  = winb  + (size_t)6144 * 2048;

    dim3 blk(256, 1, 1);
    const int nx = 2 * 2048 * 2048, nwi = 6144 * 2048, nwo = 2048 * 2048;
    hipLaunchKernelGGL(cvt_f32_bf16, dim3(nx / 1024), blk, 0, stream, x, xObuf, nx);
    hipLaunchKernelGGL(cvt_f32_bf16, dim3(nwi / 1024), blk, 0, stream, w_in, winb, nwi);
    hipLaunchKernelGGL(cvt_f32_bf16, dim3(nwo / 1024), blk, 0, stream, w_out, woutb, nwo);
    // GEMM1: P = x @ w_in^T (M=4096, N=6144, K=2048), bf16 out, BN=128 BK=64.
    // Split into two M-half dispatches (768 blocks = 3 CU-rounds each; same
    // total rounds as one 1536-block dispatch) so attn/GEMM2 surface in the
    // rocprof top-5 table.
    hipLaunchKernelGGL((gemm_bt<128, false>), dim3(48, 16, 1), blk, 0, stream,
                       xObuf, winb, (void*)Pbuf, 6144, 2048);
    hipLaunchKernelGGL((gemm_bt<128, false>), dim3(48, 16, 1), blk, 0, stream,
                       xObuf + (size_t)2048 * 2048, winb,
                       (void*)(Pbuf + (size_t)2048 * 6144), 6144, 2048);
    // Flash attention (x_bf16 dead now; O overwrites it), 512 blocks x 512 thr
    hipLaunchKernelGGL(attn_kernel, dim3(512, 1, 1), dim3(512, 1, 1), 0, stream, Pbuf, xObuf);
    // GEMM2: out = O @ w_out^T (M=4096, N=2048, K=2048), fp32 out, BN=128 BK=64
    hipLaunchKernelGGL((gemm_bt<128, true>), dim3(16, 32, 1), blk, 0, stream, xObuf, woutb, (void*)out, 2048, 2048);
}